// Round 1
// baseline (368.836 us; speedup 1.0000x reference)
//
#include <hip/hip_runtime.h>
#include <hip/hip_bf16.h>
#include <stdint.h>

// ---------------------------------------------------------------------------
// TransformerDecoderBlock on MI355X (gfx950).  B=2, T=2048, C=1024, H=16, hd=64.
// R8: N=1024 GEMMs (Wo, FF2) -> 64x64 tiles, 4 blocks/CU.
// R9: gemm6464_k -> 3-buffer ring, depth-2 prefetch, counted s_waitcnt vmcnt(4)
//     (never drain to 0 in main loop). Attacks the vmcnt(0)-drain-at-barrier
//     stall (MfmaUtil 25%, VALUBusy 22%, both pipes idle = latency-bound).
// ---------------------------------------------------------------------------

typedef __attribute__((ext_vector_type(8))) short bf16x8;   // 8 bf16 in 4 VGPRs
typedef __attribute__((ext_vector_type(4))) float f32x4;

#define MFMA16(a, b, c) __builtin_amdgcn_mfma_f32_16x16x32_bf16((a), (b), (c), 0, 0, 0)

__device__ __forceinline__ void gload16(const void* g, void* l) {
    __builtin_amdgcn_global_load_lds(
        (const __attribute__((address_space(1))) char*)g,
        (__attribute__((address_space(3))) char*)l, 16, 0, 0);
}

// XCD-aware remap: contiguous chunk of work per XCD (XCD = dispatch id % 8).
__device__ __forceinline__ int xcd_swizzle(int flat, int nblk) {
    if ((nblk & 7) == 0) {
        const int per = nblk >> 3;
        flat = (flat & 7) * per + (flat >> 3);
    }
    return flat;
}

// ---------------- merged transpose + fp32->bf16 for all 4 weights -----------
__global__ __launch_bounds__(256) void tconv_all(
    const float* __restrict__ w0, __hip_bfloat16* __restrict__ o0,   // 1024x3072
    const float* __restrict__ w1, __hip_bfloat16* __restrict__ o1,   // 1024x1024
    const float* __restrict__ w2, __hip_bfloat16* __restrict__ o2,   // 1024x4096
    const float* __restrict__ w3, __hip_bfloat16* __restrict__ o3) { // 4096x1024
    __shared__ float tile[32][33];
    const int f = blockIdx.x;
    const float* in; __hip_bfloat16* out; int K, N, nx, t;
    if (f < 3072)      { in = w0; out = o0; K = 1024; N = 3072; nx = 96;  t = f; }
    else if (f < 4096) { in = w1; out = o1; K = 1024; N = 1024; nx = 32;  t = f - 3072; }
    else if (f < 8192) { in = w2; out = o2; K = 1024; N = 4096; nx = 128; t = f - 4096; }
    else               { in = w3; out = o3; K = 4096; N = 1024; nx = 32;  t = f - 8192; }
    const int n0 = (t % nx) * 32, k0 = (t / nx) * 32;
    const int tx = threadIdx.x, ty = threadIdx.y;   // block (32, 8)
    for (int i = ty; i < 32; i += 8)
        tile[i][tx] = in[(size_t)(k0 + i) * N + n0 + tx];
    __syncthreads();
    for (int i = ty; i < 32; i += 8)
        out[(size_t)(n0 + i) * K + k0 + tx] = __float2bfloat16(tile[tx][i]);
}

// --------------------------------- layernorm -------------------------------
__global__ __launch_bounds__(256) void ln_k(const float* __restrict__ x,
                                            const float* __restrict__ g,
                                            const float* __restrict__ beta,
                                            __hip_bfloat16* __restrict__ out) {
    const int row = blockIdx.x;
    const int tid = threadIdx.x;
    float4 v = ((const float4*)(x + (size_t)row * 1024))[tid];
    float s  = v.x + v.y + v.z + v.w;
    float s2 = v.x * v.x + v.y * v.y + v.z * v.z + v.w * v.w;
    for (int off = 1; off < 64; off <<= 1) {
        s  += __shfl_xor(s,  off, 64);
        s2 += __shfl_xor(s2, off, 64);
    }
    __shared__ float ss[4], ss2[4];
    const int w = tid >> 6, lane = tid & 63;
    if (lane == 0) { ss[w] = s; ss2[w] = s2; }
    __syncthreads();
    s  = ss[0] + ss[1] + ss[2] + ss[3];
    s2 = ss2[0] + ss2[1] + ss2[2] + ss2[3];
    const float mu  = s * (1.0f / 1024.0f);
    const float var = s2 * (1.0f / 1024.0f) - mu * mu;
    const float rs  = rsqrtf(var + 1e-5f);
    float4 gv = ((const float4*)g)[tid];
    float4 bv = ((const float4*)beta)[tid];
    __hip_bfloat16* o = out + (size_t)row * 1024 + tid * 4;
    o[0] = __float2bfloat16((v.x - mu) * rs * gv.x + bv.x);
    o[1] = __float2bfloat16((v.y - mu) * rs * gv.y + bv.y);
    o[2] = __float2bfloat16((v.z - mu) * rs * gv.z + bv.z);
    o[3] = __float2bfloat16((v.w - mu) * rs * gv.w + bv.w);
}

// ------------------- GEMM, BM=128 BN=128 BK=64, dbuf 1-barrier ---------------
template <int BIAS, int RELU, int RESID, int OUTBF>
__global__ __launch_bounds__(256, 2) void gemm_k(const __hip_bfloat16* __restrict__ A,
                                                 const __hip_bfloat16* __restrict__ Bt,
                                                 const float* __restrict__ bias,
                                                 const float* __restrict__ resid,
                                                 void* __restrict__ out,
                                                 int M, int N, int K) {
    __align__(16) __shared__ __hip_bfloat16 As[2][128 * 64];
    __align__(16) __shared__ __hip_bfloat16 Bs[2][128 * 64];

    const int tid  = threadIdx.x;
    const int lane = tid & 63, w = tid >> 6;
    const int wm = w >> 1, wn = w & 1;
    const int nbx = gridDim.x;
    const int flat = xcd_swizzle(blockIdx.y * nbx + blockIdx.x, nbx * gridDim.y);
    const int m0 = (flat / nbx) * 128, n0 = (flat % nbx) * 128;
    const int l16 = lane & 15, quad = lane >> 4;

    const int srw = lane >> 3;                 // 0..7
    const int scn = ((lane & 7) - srw) & 7;    // source chunk (swizzled)

    const __hip_bfloat16* ga[4];
    const __hip_bfloat16* gb[4];
#pragma unroll
    for (int i = 0; i < 4; i++) {
        const int row = i * 32 + w * 8 + srw;
        ga[i] = A  + (size_t)(m0 + row) * K + scn * 8;
        gb[i] = Bt + (size_t)(n0 + row) * K + scn * 8;
    }

    int offA[2][4], offB[2][4];
#pragma unroll
    for (int s = 0; s < 2; s++)
#pragma unroll
        for (int t = 0; t < 4; t++) {
            const int rA = wm * 64 + t * 16 + l16;
            offA[s][t] = (rA * 8 + ((s * 4 + quad + (rA & 7)) & 7)) * 16;
            const int rB = wn * 64 + t * 16 + l16;
            offB[s][t] = (rB * 8 + ((s * 4 + quad + (rB & 7)) & 7)) * 16;
        }

    f32x4 acc[4][4] = {};

#pragma unroll
    for (int i = 0; i < 4; i++) {
        gload16(ga[i], As[0] + (i * 256 + w * 64) * 8);
        gload16(gb[i], Bs[0] + (i * 256 + w * 64) * 8);
        ga[i] += 64; gb[i] += 64;
    }

    const int niter = K >> 6;
    for (int it = 0; it < niter; it++) {
        const int buf = it & 1;
        __syncthreads();   // drains prefetch into buf (issued prev iter)
        if (it + 1 < niter) {
#pragma unroll
            for (int i = 0; i < 4; i++) {
                gload16(ga[i], As[buf ^ 1] + (i * 256 + w * 64) * 8);
                gload16(gb[i], Bs[buf ^ 1] + (i * 256 + w * 64) * 8);
                ga[i] += 64; gb[i] += 64;
            }
        }

#pragma unroll
        for (int s = 0; s < 2; s++) {
            bf16x8 af[4], bfr[4];
#pragma unroll
            for (int t = 0; t < 4; t++) {
                af[t]  = *(const bf16x8*)((const char*)As[buf] + offA[s][t]);
                bfr[t] = *(const bf16x8*)((const char*)Bs[buf] + offB[s][t]);
            }
#pragma unroll
            for (int mt = 0; mt < 4; mt++)
#pragma unroll
                for (int nt = 0; nt < 4; nt++)
                    acc[mt][nt] = MFMA16(af[mt], bfr[nt], acc[mt][nt]);
        }
    }

#pragma unroll
    for (int mt = 0; mt < 4; mt++)
#pragma unroll
        for (int nt = 0; nt < 4; nt++) {
            const int row = m0 + wm * 64 + mt * 16 + quad * 4;
            const int col = n0 + wn * 64 + nt * 16 + l16;
            const float bv = BIAS ? bias[col] : 0.0f;
#pragma unroll
            for (int r = 0; r < 4; r++) {
                float v = acc[mt][nt][r] + bv;
                if (RELU) v = v > 0.0f ? v : 0.0f;
                const size_t idx = (size_t)(row + r) * N + col;
                if (RESID) v += resid[idx];
                if (OUTBF) ((__hip_bfloat16*)out)[idx] = __float2bfloat16(v);
                else       ((float*)out)[idx] = v;
            }
        }
}

// ------------- GEMM, BM=64 BN=64 BK=64, 3-buffer ring, counted vmcnt --------
// For N=1024 outputs: grid (N/64)x(M/64) = 1024 blocks.
// Depth-2 prefetch: loads for tile it+2 issued at iter it; s_waitcnt vmcnt(4)
// waits only for the tile about to be consumed -- never drains in main loop.
// WAR safety: buffer refilled at iter it was last ds_read at it-1; every
// wave's reads complete before it reaches the iter-it barrier (MFMA consumers
// force the lgkm waits), so the single barrier is the reads-done fence.
template <int BIAS, int RELU, int RESID, int OUTBF>
__global__ __launch_bounds__(256, 3) void gemm6464_k(const __hip_bfloat16* __restrict__ A,
                                                     const __hip_bfloat16* __restrict__ Bt,
                                                     const float* __restrict__ bias,
                                                     const float* __restrict__ resid,
                                                     void* __restrict__ out,
                                                     int M, int N, int K) {
    __align__(16) __shared__ __hip_bfloat16 As[3][64 * 64];
    __align__(16) __shared__ __hip_bfloat16 Bs[3][64 * 64];

    const int tid  = threadIdx.x;
    const int lane = tid & 63, w = tid >> 6;
    const int wm = w >> 1, wn = w & 1;             // 2x2 wave grid of 32x32
    const int nbx = gridDim.x;
    const int flat = xcd_swizzle(blockIdx.y * nbx + blockIdx.x, nbx * gridDim.y);
    const int m0 = (flat / nbx) * 64, n0 = (flat % nbx) * 64;
    const int l16 = lane & 15, quad = lane >> 4;

    const int srw = lane >> 3;
    const int scn = ((lane & 7) - srw) & 7;

    const __hip_bfloat16* ga[2];
    const __hip_bfloat16* gb[2];
#pragma unroll
    for (int i = 0; i < 2; i++) {
        const int row = i * 32 + w * 8 + srw;
        ga[i] = A  + (size_t)(m0 + row) * K + scn * 8;
        gb[i] = Bt + (size_t)(n0 + row) * K + scn * 8;
    }

    int offA[2][2], offB[2][2];
#pragma unroll
    for (int s = 0; s < 2; s++)
#pragma unroll
        for (int t = 0; t < 2; t++) {
            const int rA = wm * 32 + t * 16 + l16;
            offA[s][t] = (rA * 8 + ((s * 4 + quad + (rA & 7)) & 7)) * 16;
            const int rB = wn * 32 + t * 16 + l16;
            offB[s][t] = (rB * 8 + ((s * 4 + quad + (rB & 7)) & 7)) * 16;
        }

    f32x4 acc[2][2] = {};

    const int niter = K >> 6;

    // prologue: fill buffers 0 and 1 (4 VMEM ops each per thread -> 8 in flight)
#pragma unroll
    for (int i = 0; i < 2; i++) {
        gload16(ga[i], As[0] + (i * 256 + w * 64) * 8);
        gload16(gb[i], Bs[0] + (i * 256 + w * 64) * 8);
        ga[i] += 64; gb[i] += 64;
    }
    if (niter > 1) {
#pragma unroll
        for (int i = 0; i < 2; i++) {
            gload16(ga[i], As[1] + (i * 256 + w * 64) * 8);
            gload16(gb[i], Bs[1] + (i * 256 + w * 64) * 8);
            ga[i] += 64; gb[i] += 64;
        }
    }

    int cur = 0, nxt = 1, pre = 2;
    for (int it = 0; it < niter; it++) {
        // wait only for the 4 loads of the tile we're about to consume;
        // keep the next tile's 4 loads in flight across the barrier.
        if (it + 1 < niter)
            asm volatile("s_waitcnt vmcnt(4)" ::: "memory");
        else
            asm volatile("s_waitcnt vmcnt(0)" ::: "memory");
        __builtin_amdgcn_s_barrier();
        asm volatile("" ::: "memory");

        if (it + 2 < niter) {
#pragma unroll
            for (int i = 0; i < 2; i++) {
                gload16(ga[i], As[pre] + (i * 256 + w * 64) * 8);
                gload16(gb[i], Bs[pre] + (i * 256 + w * 64) * 8);
                ga[i] += 64; gb[i] += 64;
            }
        }

#pragma unroll
        for (int s = 0; s < 2; s++) {
            bf16x8 af[2], bfr[2];
#pragma unroll
            for (int t = 0; t < 2; t++) {
                af[t]  = *(const bf16x8*)((const char*)As[cur] + offA[s][t]);
                bfr[t] = *(const bf16x8*)((const char*)Bs[cur] + offB[s][t]);
            }
#pragma unroll
            for (int mt = 0; mt < 2; mt++)
#pragma unroll
                for (int nt = 0; nt < 2; nt++)
                    acc[mt][nt] = MFMA16(af[mt], bfr[nt], acc[mt][nt]);
        }

        const int t0 = cur; cur = nxt; nxt = pre; pre = t0;
    }

#pragma unroll
    for (int mt = 0; mt < 2; mt++)
#pragma unroll
        for (int nt = 0; nt < 2; nt++) {
            const int row = m0 + wm * 32 + mt * 16 + quad * 4;
            const int col = n0 + wn * 32 + nt * 16 + l16;
            const float bv = BIAS ? bias[col] : 0.0f;
#pragma unroll
            for (int r = 0; r < 4; r++) {
                float v = acc[mt][nt][r] + bv;
                if (RELU) v = v > 0.0f ? v : 0.0f;
                const size_t idx = (size_t)(row + r) * N + col;
                if (RESID) v += resid[idx];
                if (OUTBF) ((__hip_bfloat16*)out)[idx] = __float2bfloat16(v);
                else       ((float*)out)[idx] = v;
            }
        }
}

// ----------------------- V transpose: qkv -> Vt[bh][d][T] -------------------
__global__ __launch_bounds__(256) void vtrans_k(const __hip_bfloat16* __restrict__ qkv,
                                                __hip_bfloat16* __restrict__ vt) {
    const int T = 2048, C3 = 3072;
    const int bh = blockIdx.y, b = bh >> 4, h = bh & 15;
    const int t0 = blockIdx.x * 64;
    const int tx = threadIdx.x, ty = threadIdx.y;   // block (64, 4)
    __shared__ __hip_bfloat16 tile[64][65];
#pragma unroll
    for (int j = 0; j < 16; j++) {
        const int tl = ty * 16 + j;
        tile[tl][tx] = qkv[(size_t)(b * T + t0 + tl) * C3 + 2048 + h * 64 + tx];
    }
    __syncthreads();
#pragma unroll
    for (int j = 0; j < 16; j++) {
        const int d = ty * 16 + j;
        vt[((size_t)bh * 64 + d) * 2048 + t0 + tx] = tile[tx][d];
    }
}

// ------------------------------ flash attention -----------------------------
__global__ __launch_bounds__(256, 3) void attn_k(const __hip_bfloat16* __restrict__ qkv,
                                                 const __hip_bfloat16* __restrict__ vt,
                                                 __hip_bfloat16* __restrict__ outp) {
    const int T = 2048, C3 = 3072;
    const int bh = blockIdx.x, b = bh >> 4, h = bh & 15;
    const int qt = 31 - blockIdx.y;           // heavy q-tiles dispatched first
    const int q0 = qt * 64;
    const int tid = threadIdx.x, lane = tid & 63, w = tid >> 6;
    const int l16 = lane & 15, quad = lane >> 4;

    __align__(16) __shared__ __hip_bfloat16 Ks[2][64 * 64];   // swizzled [key][d]
    __align__(16) __shared__ __hip_bfloat16 Vs[2][64 * 64];   // swizzled [d][key]
    __align__(16) __shared__ __hip_bfloat16 Pw[4][16 * 72];   // per-wave P

    const float sc = 0.125f * 1.44269504f;
    bf16x8 qf0, qf1;
    {
        const __hip_bfloat16* qp =
            qkv + (size_t)(b * T + q0 + w * 16 + l16) * C3 + h * 64;
        bf16x8 a = *(const bf16x8*)(qp + quad * 8);
        bf16x8 c = *(const bf16x8*)(qp + 32 + quad * 8);
#pragma unroll
        for (int i = 0; i < 8; i++) {
            union { unsigned int u; float f; } ua, uc;
            ua.u = ((unsigned int)(unsigned short)a[i]) << 16;
            uc.u = ((unsigned int)(unsigned short)c[i]) << 16;
            qf0[i] = (short)(__bfloat16_as_ushort(__float2bfloat16(ua.f * sc)));
            qf1[i] = (short)(__bfloat16_as_ushort(__float2bfloat16(uc.f * sc)));
        }
    }

    const int srw = lane >> 3;
    const int scn = ((lane & 7) - srw) & 7;
    const __hip_bfloat16* kp[2];
    const __hip_bfloat16* vp[2];
#pragma unroll
    for (int i = 0; i < 2; i++) {
        const int row = i * 32 + w * 8 + srw;
        kp[i] = qkv + (size_t)(b * T + row) * C3 + 1024 + h * 64 + scn * 8;
        vp[i] = vt + ((size_t)bh * 64 + row) * 2048 + scn * 8;
    }

    int offK[2][4];
#pragma unroll
    for (int s = 0; s < 2; s++)
#pragma unroll
        for (int t = 0; t < 4; t++) {
            const int rr = t * 16 + l16;
            offK[s][t] = (rr * 8 + ((s * 4 + quad + (rr & 7)) & 7)) * 16;
        }

    f32x4 oacc[4] = {};
    float lpart[4] = {0.0f, 0.0f, 0.0f, 0.0f};

#pragma unroll
    for (int i = 0; i < 2; i++) {
        gload16(kp[i], Ks[0] + (i * 256 + w * 64) * 8);
        gload16(vp[i], Vs[0] + (i * 256 + w * 64) * 8);
    }

    for (int kt = 0; kt <= qt; kt++) {
        const int buf = kt & 1;
        __syncthreads();
        if (kt < qt) {
#pragma unroll
            for (int i = 0; i < 2; i++) {
                gload16(kp[i] + (size_t)(kt + 1) * 64 * C3,
                        Ks[buf ^ 1] + (i * 256 + w * 64) * 8);
                gload16(vp[i] + (kt + 1) * 64,
                        Vs[buf ^ 1] + (i * 256 + w * 64) * 8);
            }
        }

        f32x4 s4[4];
#pragma unroll
        for (int nt = 0; nt < 4; nt++) {
            bf16x8 kf0 = *(const bf16x8*)((const char*)Ks[buf] + offK[0][nt]);
            bf16x8 kf1 = *(const bf16x8*)((const char*)Ks[buf] + offK[1][nt]);
            f32x4 z = {};
            z = MFMA16(qf0, kf0, z);
            z = MFMA16(qf1, kf1, z);
            s4[nt] = z;
        }

        const bool diag = (kt == qt);
        const int myrow = w * 16 + quad * 4;
#pragma unroll
        for (int nt = 0; nt < 4; nt++) {
            const int col = nt * 16 + l16;
#pragma unroll
            for (int r = 0; r < 4; r++) {
                float p = exp2f(s4[nt][r]);
                if (diag && col > myrow + r) p = 0.0f;
                lpart[r] += p;
                Pw[w][(quad * 4 + r) * 72 + col] = __float2bfloat16(p);
            }
        }

        asm volatile("s_waitcnt lgkmcnt(0)" ::: "memory");

        bf16x8 pf0 = *(const bf16x8*)(&Pw[w][l16 * 72 + quad * 8]);
        bf16x8 pf1 = *(const bf16x8*)(&Pw[w][l16 * 72 + 32 + quad * 8]);
#pragma unroll
        for (int dt = 0; dt < 4; dt++) {
            bf16x8 vf0 = *(const bf16x8*)((const char*)Vs[buf] + offK[0][dt]);
            bf16x8 vf1 = *(const bf16x8*)((const char*)Vs[buf] + offK[1][dt]);
            oacc[dt] = MFMA16(pf0, vf0, oacc[dt]);
            oacc[dt] = MFMA16(pf1, vf1, oacc[dt]);
        }
    }

#pragma unroll
    for (int off = 1; off < 16; off <<= 1)
#pragma unroll
        for (int r = 0; r < 4; r++)
            lpart[r] += __shfl_xor(lpart[r], off, 64);

    float rl[4];
#pragma unroll
    for (int r = 0; r < 4; r++) rl[r] = 1.0f / lpart[r];
#pragma unroll
    for (int dt = 0; dt < 4; dt++)
#pragma unroll
        for (int r = 0; r < 4; r++) {
            const int row = q0 + w * 16 + quad * 4 + r;
            outp[(size_t)(b * T + row) * 1024 + h * 64 + dt * 16 + l16] =
                __float2bfloat16(oacc[dt][r] * rl[r]);
        }
}

// --------------------------------- launcher --------------------------------
extern "C" void kernel_launch(void* const* d_in, const int* in_sizes, int n_in,
                              void* d_out, int out_size, void* d_ws, size_t ws_size,
                              hipStream_t stream) {
    const float* x     = (const float*)d_in[0];
    const float* Wqkv  = (const float*)d_in[1];
    const float* Wo    = (const float*)d_in[2];
    const float* b_o   = (const float*)d_in[3];
    const float* g1    = (const float*)d_in[4];
    const float* beta1 = (const float*)d_in[5];
    const float* g2    = (const float*)d_in[6];
    const float* beta2 = (const float*)d_in[7];
    const float* Wff1  = (const float*)d_in[8];
    const float* bff1  = (const float*)d_in[9];
    const float* Wff2  = (const float*)d_in[10];
    const float* bff2  = (const float*)d_in[11];

    char* ws = (char*)d_ws;
    size_t off = 0;
    auto alloc = [&](size_t bytes) {
        void* p = ws + off;
        off += (bytes + 255) & ~(size_t)255;
        return p;
    };
    __hip_bfloat16* Wqkv_t = (__hip_bfloat16*)alloc(3072ULL * 1024 * 2);
    __hip_bfloat16* Wo_t   = (__hip_bfloat16*)alloc(1024ULL * 1024 * 2);
    __hip_bfloat16* Wff1_t = (__hip_bfloat16*)alloc(4096ULL * 1024 * 2);
    __hip_bfloat16* Wff2_t = (__hip_bfloat16*)alloc(1024ULL * 4096 * 2);
    __hip_bfloat16* h_bf   = (__hip_bfloat16*)alloc(4096ULL * 1024 * 2);
    __hip_bfloat16* qkv_bf = (__hip_bfloat16*)alloc(4096ULL * 3072 * 2);
    __hip_bfloat16* att_bf = (__hip_bfloat16*)alloc(4096ULL * 1024 * 2);
    float*          x2     = (float*)alloc(4096ULL * 1024 * 4);
    __hip_bfloat16* ff1_bf = qkv_bf;              // dead by FF time
    __hip_bfloat16* vt     = (__hip_bfloat16*)x2; // dead before Wo-gemm writes x2

    tconv_all<<<12288, dim3(32, 8), 0, stream>>>(Wqkv, Wqkv_t, Wo, Wo_t,
                                                 Wff1, Wff1_t, Wff2, Wff2_t);

    ln_k<<<4096, 256, 0, stream>>>(x, g1, beta1, h_bf);
    gemm_k<0, 0, 0, 1><<<dim3(3072 / 128, 4096 / 128), 256, 0, stream>>>(
        h_bf, Wqkv_t, nullptr, nullptr, qkv_bf, 4096, 3072, 1024);
    vtrans_k<<<dim3(32, 32), dim3(64, 4), 0, stream>>>(qkv_bf, vt);
    attn_k<<<dim3(32, 32), 256, 0, stream>>>(qkv_bf, vt, att_bf);
    gemm6464_k<1, 0, 1, 0><<<dim3(1024 / 64, 4096 / 64), 256, 0, stream>>>(
        att_bf, Wo_t, b_o, x, x2, 4096, 1024, 1024);
    ln_k<<<4096, 256, 0, stream>>>(x2, g2, beta2, h_bf);
    gemm_k<1, 1, 0, 1><<<dim3(4096 / 128, 4096 / 128), 256, 0, stream>>>(
        h_bf, Wff1_t, bff1, nullptr, ff1_bf, 4096, 4096, 1024);
    gemm6464_k<1, 0, 1, 0><<<dim3(1024 / 64, 4096 / 64), 256, 0, stream>>>(
        ff1_bf, Wff2_t, bff2, x2, (float*)d_out, 4096, 1024, 4096);
}

// Round 2
// 333.853 us; speedup vs baseline: 1.1048x; 1.1048x over previous
//
#include <hip/hip_runtime.h>
#include <hip/hip_bf16.h>
#include <stdint.h>

// ---------------------------------------------------------------------------
// TransformerDecoderBlock on MI355X (gfx950).  B=2, T=2048, C=1024, H=16, hd=64.
// R8: N=1024 GEMMs (Wo, FF2) -> 64x64 tiles, 4 blocks/CU.        [53.5us FF2]
// R9: 3-buffer ring + counted vmcnt -> FAILED (88us): runtime buffer index
//     killed codegen (VGPR 44->68, no static LDS offsets). Reverted.
// R10: theory = 64^2 tile is LDS-read-pipe bound (1.0 ds_read_b128/MFMA =
//     ~12cy/read vs observed 15.7cy/MFMA). New gemm12864_k: BM=128 BN=64,
//     wave-tile 64x32 -> 0.75 reads/MFMA, 2x compute per barrier. Same
//     proven 2-buffer drain-0 skeleton as R8.
// ---------------------------------------------------------------------------

typedef __attribute__((ext_vector_type(8))) short bf16x8;   // 8 bf16 in 4 VGPRs
typedef __attribute__((ext_vector_type(4))) float f32x4;

#define MFMA16(a, b, c) __builtin_amdgcn_mfma_f32_16x16x32_bf16((a), (b), (c), 0, 0, 0)

__device__ __forceinline__ void gload16(const void* g, void* l) {
    __builtin_amdgcn_global_load_lds(
        (const __attribute__((address_space(1))) char*)g,
        (__attribute__((address_space(3))) char*)l, 16, 0, 0);
}

// XCD-aware remap: contiguous chunk of work per XCD (XCD = dispatch id % 8).
__device__ __forceinline__ int xcd_swizzle(int flat, int nblk) {
    if ((nblk & 7) == 0) {
        const int per = nblk >> 3;
        flat = (flat & 7) * per + (flat >> 3);
    }
    return flat;
}

// ---------------- merged transpose + fp32->bf16 for all 4 weights -----------
__global__ __launch_bounds__(256) void tconv_all(
    const float* __restrict__ w0, __hip_bfloat16* __restrict__ o0,   // 1024x3072
    const float* __restrict__ w1, __hip_bfloat16* __restrict__ o1,   // 1024x1024
    const float* __restrict__ w2, __hip_bfloat16* __restrict__ o2,   // 1024x4096
    const float* __restrict__ w3, __hip_bfloat16* __restrict__ o3) { // 4096x1024
    __shared__ float tile[32][33];
    const int f = blockIdx.x;
    const float* in; __hip_bfloat16* out; int K, N, nx, t;
    if (f < 3072)      { in = w0; out = o0; K = 1024; N = 3072; nx = 96;  t = f; }
    else if (f < 4096) { in = w1; out = o1; K = 1024; N = 1024; nx = 32;  t = f - 3072; }
    else if (f < 8192) { in = w2; out = o2; K = 1024; N = 4096; nx = 128; t = f - 4096; }
    else               { in = w3; out = o3; K = 4096; N = 1024; nx = 32;  t = f - 8192; }
    const int n0 = (t % nx) * 32, k0 = (t / nx) * 32;
    const int tx = threadIdx.x, ty = threadIdx.y;   // block (32, 8)
    for (int i = ty; i < 32; i += 8)
        tile[i][tx] = in[(size_t)(k0 + i) * N + n0 + tx];
    __syncthreads();
    for (int i = ty; i < 32; i += 8)
        out[(size_t)(n0 + i) * K + k0 + tx] = __float2bfloat16(tile[tx][i]);
}

// --------------------------------- layernorm -------------------------------
__global__ __launch_bounds__(256) void ln_k(const float* __restrict__ x,
                                            const float* __restrict__ g,
                                            const float* __restrict__ beta,
                                            __hip_bfloat16* __restrict__ out) {
    const int row = blockIdx.x;
    const int tid = threadIdx.x;
    float4 v = ((const float4*)(x + (size_t)row * 1024))[tid];
    float s  = v.x + v.y + v.z + v.w;
    float s2 = v.x * v.x + v.y * v.y + v.z * v.z + v.w * v.w;
    for (int off = 1; off < 64; off <<= 1) {
        s  += __shfl_xor(s,  off, 64);
        s2 += __shfl_xor(s2, off, 64);
    }
    __shared__ float ss[4], ss2[4];
    const int w = tid >> 6, lane = tid & 63;
    if (lane == 0) { ss[w] = s; ss2[w] = s2; }
    __syncthreads();
    s  = ss[0] + ss[1] + ss[2] + ss[3];
    s2 = ss2[0] + ss2[1] + ss2[2] + ss2[3];
    const float mu  = s * (1.0f / 1024.0f);
    const float var = s2 * (1.0f / 1024.0f) - mu * mu;
    const float rs  = rsqrtf(var + 1e-5f);
    float4 gv = ((const float4*)g)[tid];
    float4 bv = ((const float4*)beta)[tid];
    __hip_bfloat16* o = out + (size_t)row * 1024 + tid * 4;
    o[0] = __float2bfloat16((v.x - mu) * rs * gv.x + bv.x);
    o[1] = __float2bfloat16((v.y - mu) * rs * gv.y + bv.y);
    o[2] = __float2bfloat16((v.z - mu) * rs * gv.z + bv.z);
    o[3] = __float2bfloat16((v.w - mu) * rs * gv.w + bv.w);
}

// ------------------- GEMM, BM=128 BN=128 BK=64, dbuf 1-barrier ---------------
template <int BIAS, int RELU, int RESID, int OUTBF>
__global__ __launch_bounds__(256, 2) void gemm_k(const __hip_bfloat16* __restrict__ A,
                                                 const __hip_bfloat16* __restrict__ Bt,
                                                 const float* __restrict__ bias,
                                                 const float* __restrict__ resid,
                                                 void* __restrict__ out,
                                                 int M, int N, int K) {
    __align__(16) __shared__ __hip_bfloat16 As[2][128 * 64];
    __align__(16) __shared__ __hip_bfloat16 Bs[2][128 * 64];

    const int tid  = threadIdx.x;
    const int lane = tid & 63, w = tid >> 6;
    const int wm = w >> 1, wn = w & 1;
    const int nbx = gridDim.x;
    const int flat = xcd_swizzle(blockIdx.y * nbx + blockIdx.x, nbx * gridDim.y);
    const int m0 = (flat / nbx) * 128, n0 = (flat % nbx) * 128;
    const int l16 = lane & 15, quad = lane >> 4;

    const int srw = lane >> 3;                 // 0..7
    const int scn = ((lane & 7) - srw) & 7;    // source chunk (swizzled)

    const __hip_bfloat16* ga[4];
    const __hip_bfloat16* gb[4];
#pragma unroll
    for (int i = 0; i < 4; i++) {
        const int row = i * 32 + w * 8 + srw;
        ga[i] = A  + (size_t)(m0 + row) * K + scn * 8;
        gb[i] = Bt + (size_t)(n0 + row) * K + scn * 8;
    }

    int offA[2][4], offB[2][4];
#pragma unroll
    for (int s = 0; s < 2; s++)
#pragma unroll
        for (int t = 0; t < 4; t++) {
            const int rA = wm * 64 + t * 16 + l16;
            offA[s][t] = (rA * 8 + ((s * 4 + quad + (rA & 7)) & 7)) * 16;
            const int rB = wn * 64 + t * 16 + l16;
            offB[s][t] = (rB * 8 + ((s * 4 + quad + (rB & 7)) & 7)) * 16;
        }

    f32x4 acc[4][4] = {};

#pragma unroll
    for (int i = 0; i < 4; i++) {
        gload16(ga[i], As[0] + (i * 256 + w * 64) * 8);
        gload16(gb[i], Bs[0] + (i * 256 + w * 64) * 8);
        ga[i] += 64; gb[i] += 64;
    }

    const int niter = K >> 6;
    for (int it = 0; it < niter; it++) {
        const int buf = it & 1;
        __syncthreads();   // drains prefetch into buf (issued prev iter)
        if (it + 1 < niter) {
#pragma unroll
            for (int i = 0; i < 4; i++) {
                gload16(ga[i], As[buf ^ 1] + (i * 256 + w * 64) * 8);
                gload16(gb[i], Bs[buf ^ 1] + (i * 256 + w * 64) * 8);
                ga[i] += 64; gb[i] += 64;
            }
        }

#pragma unroll
        for (int s = 0; s < 2; s++) {
            bf16x8 af[4], bfr[4];
#pragma unroll
            for (int t = 0; t < 4; t++) {
                af[t]  = *(const bf16x8*)((const char*)As[buf] + offA[s][t]);
                bfr[t] = *(const bf16x8*)((const char*)Bs[buf] + offB[s][t]);
            }
#pragma unroll
            for (int mt = 0; mt < 4; mt++)
#pragma unroll
                for (int nt = 0; nt < 4; nt++)
                    acc[mt][nt] = MFMA16(af[mt], bfr[nt], acc[mt][nt]);
        }
    }

#pragma unroll
    for (int mt = 0; mt < 4; mt++)
#pragma unroll
        for (int nt = 0; nt < 4; nt++) {
            const int row = m0 + wm * 64 + mt * 16 + quad * 4;
            const int col = n0 + wn * 64 + nt * 16 + l16;
            const float bv = BIAS ? bias[col] : 0.0f;
#pragma unroll
            for (int r = 0; r < 4; r++) {
                float v = acc[mt][nt][r] + bv;
                if (RELU) v = v > 0.0f ? v : 0.0f;
                const size_t idx = (size_t)(row + r) * N + col;
                if (RESID) v += resid[idx];
                if (OUTBF) ((__hip_bfloat16*)out)[idx] = __float2bfloat16(v);
                else       ((float*)out)[idx] = v;
            }
        }
}

// ------------- GEMM, BM=128 BN=64 BK=64, dbuf 1-barrier (R10) ---------------
// For N=1024 outputs: grid (N/64)x(M/128) = 16x32 = 512 blocks -> 2/CU.
// Wave grid 2x2, wave-tile 64x32: per K-half 6 ds_read_b128 : 8 MFMA
// (0.75 reads/MFMA vs 1.0 in the old 64^2 tile -> off the LDS-pipe ceiling).
template <int BIAS, int RELU, int RESID, int OUTBF>
__global__ __launch_bounds__(256, 2) void gemm12864_k(const __hip_bfloat16* __restrict__ A,
                                                      const __hip_bfloat16* __restrict__ Bt,
                                                      const float* __restrict__ bias,
                                                      const float* __restrict__ resid,
                                                      void* __restrict__ out,
                                                      int M, int N, int K) {
    __align__(16) __shared__ __hip_bfloat16 As[2][128 * 64];
    __align__(16) __shared__ __hip_bfloat16 Bs[2][64 * 64];

    const int tid  = threadIdx.x;
    const int lane = tid & 63, w = tid >> 6;
    const int wm = w >> 1, wn = w & 1;             // 2x2 waves, wave-tile 64x32
    const int nbx = gridDim.x;
    const int flat = xcd_swizzle(blockIdx.y * nbx + blockIdx.x, nbx * gridDim.y);
    const int m0 = (flat / nbx) * 128, n0 = (flat % nbx) * 64;
    const int l16 = lane & 15, quad = lane >> 4;

    const int srw = lane >> 3;
    const int scn = ((lane & 7) - srw) & 7;

    const __hip_bfloat16* ga[4];
    const __hip_bfloat16* gb[2];
#pragma unroll
    for (int i = 0; i < 4; i++) {
        const int row = i * 32 + w * 8 + srw;
        ga[i] = A + (size_t)(m0 + row) * K + scn * 8;
    }
#pragma unroll
    for (int i = 0; i < 2; i++) {
        const int row = i * 32 + w * 8 + srw;
        gb[i] = Bt + (size_t)(n0 + row) * K + scn * 8;
    }

    int offA[2][4], offB[2][2];
#pragma unroll
    for (int s = 0; s < 2; s++) {
#pragma unroll
        for (int t = 0; t < 4; t++) {
            const int rA = wm * 64 + t * 16 + l16;       // 0..127
            offA[s][t] = (rA * 8 + ((s * 4 + quad + (rA & 7)) & 7)) * 16;
        }
#pragma unroll
        for (int t = 0; t < 2; t++) {
            const int rB = wn * 32 + t * 16 + l16;       // 0..63
            offB[s][t] = (rB * 8 + ((s * 4 + quad + (rB & 7)) & 7)) * 16;
        }
    }

    f32x4 acc[4][2] = {};

#pragma unroll
    for (int i = 0; i < 4; i++) {
        gload16(ga[i], As[0] + (i * 256 + w * 64) * 8);
        ga[i] += 64;
    }
#pragma unroll
    for (int i = 0; i < 2; i++) {
        gload16(gb[i], Bs[0] + (i * 256 + w * 64) * 8);
        gb[i] += 64;
    }

    const int niter = K >> 6;
    for (int it = 0; it < niter; it++) {
        const int buf = it & 1;
        __syncthreads();   // drains prefetch into buf (issued prev iter)
        if (it + 1 < niter) {
#pragma unroll
            for (int i = 0; i < 4; i++) {
                gload16(ga[i], As[buf ^ 1] + (i * 256 + w * 64) * 8);
                ga[i] += 64;
            }
#pragma unroll
            for (int i = 0; i < 2; i++) {
                gload16(gb[i], Bs[buf ^ 1] + (i * 256 + w * 64) * 8);
                gb[i] += 64;
            }
        }

#pragma unroll
        for (int s = 0; s < 2; s++) {
            bf16x8 af[4], bfr[2];
#pragma unroll
            for (int t = 0; t < 4; t++)
                af[t]  = *(const bf16x8*)((const char*)As[buf] + offA[s][t]);
#pragma unroll
            for (int t = 0; t < 2; t++)
                bfr[t] = *(const bf16x8*)((const char*)Bs[buf] + offB[s][t]);
#pragma unroll
            for (int mt = 0; mt < 4; mt++)
#pragma unroll
                for (int nt = 0; nt < 2; nt++)
                    acc[mt][nt] = MFMA16(af[mt], bfr[nt], acc[mt][nt]);
        }
    }

#pragma unroll
    for (int mt = 0; mt < 4; mt++)
#pragma unroll
        for (int nt = 0; nt < 2; nt++) {
            const int row = m0 + wm * 64 + mt * 16 + quad * 4;
            const int col = n0 + wn * 32 + nt * 16 + l16;
            const float bv = BIAS ? bias[col] : 0.0f;
#pragma unroll
            for (int r = 0; r < 4; r++) {
                float v = acc[mt][nt][r] + bv;
                if (RELU) v = v > 0.0f ? v : 0.0f;
                const size_t idx = (size_t)(row + r) * N + col;
                if (RESID) v += resid[idx];
                if (OUTBF) ((__hip_bfloat16*)out)[idx] = __float2bfloat16(v);
                else       ((float*)out)[idx] = v;
            }
        }
}

// ----------------------- V transpose: qkv -> Vt[bh][d][T] -------------------
__global__ __launch_bounds__(256) void vtrans_k(const __hip_bfloat16* __restrict__ qkv,
                                                __hip_bfloat16* __restrict__ vt) {
    const int T = 2048, C3 = 3072;
    const int bh = blockIdx.y, b = bh >> 4, h = bh & 15;
    const int t0 = blockIdx.x * 64;
    const int tx = threadIdx.x, ty = threadIdx.y;   // block (64, 4)
    __shared__ __hip_bfloat16 tile[64][65];
#pragma unroll
    for (int j = 0; j < 16; j++) {
        const int tl = ty * 16 + j;
        tile[tl][tx] = qkv[(size_t)(b * T + t0 + tl) * C3 + 2048 + h * 64 + tx];
    }
    __syncthreads();
#pragma unroll
    for (int j = 0; j < 16; j++) {
        const int d = ty * 16 + j;
        vt[((size_t)bh * 64 + d) * 2048 + t0 + tx] = tile[tx][d];
    }
}

// ------------------------------ flash attention -----------------------------
__global__ __launch_bounds__(256, 3) void attn_k(const __hip_bfloat16* __restrict__ qkv,
                                                 const __hip_bfloat16* __restrict__ vt,
                                                 __hip_bfloat16* __restrict__ outp) {
    const int T = 2048, C3 = 3072;
    const int bh = blockIdx.x, b = bh >> 4, h = bh & 15;
    const int qt = 31 - blockIdx.y;           // heavy q-tiles dispatched first
    const int q0 = qt * 64;
    const int tid = threadIdx.x, lane = tid & 63, w = tid >> 6;
    const int l16 = lane & 15, quad = lane >> 4;

    __align__(16) __shared__ __hip_bfloat16 Ks[2][64 * 64];   // swizzled [key][d]
    __align__(16) __shared__ __hip_bfloat16 Vs[2][64 * 64];   // swizzled [d][key]
    __align__(16) __shared__ __hip_bfloat16 Pw[4][16 * 72];   // per-wave P

    const float sc = 0.125f * 1.44269504f;
    bf16x8 qf0, qf1;
    {
        const __hip_bfloat16* qp =
            qkv + (size_t)(b * T + q0 + w * 16 + l16) * C3 + h * 64;
        bf16x8 a = *(const bf16x8*)(qp + quad * 8);
        bf16x8 c = *(const bf16x8*)(qp + 32 + quad * 8);
#pragma unroll
        for (int i = 0; i < 8; i++) {
            union { unsigned int u; float f; } ua, uc;
            ua.u = ((unsigned int)(unsigned short)a[i]) << 16;
            uc.u = ((unsigned int)(unsigned short)c[i]) << 16;
            qf0[i] = (short)(__bfloat16_as_ushort(__float2bfloat16(ua.f * sc)));
            qf1[i] = (short)(__bfloat16_as_ushort(__float2bfloat16(uc.f * sc)));
        }
    }

    const int srw = lane >> 3;
    const int scn = ((lane & 7) - srw) & 7;
    const __hip_bfloat16* kp[2];
    const __hip_bfloat16* vp[2];
#pragma unroll
    for (int i = 0; i < 2; i++) {
        const int row = i * 32 + w * 8 + srw;
        kp[i] = qkv + (size_t)(b * T + row) * C3 + 1024 + h * 64 + scn * 8;
        vp[i] = vt + ((size_t)bh * 64 + row) * 2048 + scn * 8;
    }

    int offK[2][4];
#pragma unroll
    for (int s = 0; s < 2; s++)
#pragma unroll
        for (int t = 0; t < 4; t++) {
            const int rr = t * 16 + l16;
            offK[s][t] = (rr * 8 + ((s * 4 + quad + (rr & 7)) & 7)) * 16;
        }

    f32x4 oacc[4] = {};
    float lpart[4] = {0.0f, 0.0f, 0.0f, 0.0f};

#pragma unroll
    for (int i = 0; i < 2; i++) {
        gload16(kp[i], Ks[0] + (i * 256 + w * 64) * 8);
        gload16(vp[i], Vs[0] + (i * 256 + w * 64) * 8);
    }

    for (int kt = 0; kt <= qt; kt++) {
        const int buf = kt & 1;
        __syncthreads();
        if (kt < qt) {
#pragma unroll
            for (int i = 0; i < 2; i++) {
                gload16(kp[i] + (size_t)(kt + 1) * 64 * C3,
                        Ks[buf ^ 1] + (i * 256 + w * 64) * 8);
                gload16(vp[i] + (kt + 1) * 64,
                        Vs[buf ^ 1] + (i * 256 + w * 64) * 8);
            }
        }

        f32x4 s4[4];
#pragma unroll
        for (int nt = 0; nt < 4; nt++) {
            bf16x8 kf0 = *(const bf16x8*)((const char*)Ks[buf] + offK[0][nt]);
            bf16x8 kf1 = *(const bf16x8*)((const char*)Ks[buf] + offK[1][nt]);
            f32x4 z = {};
            z = MFMA16(qf0, kf0, z);
            z = MFMA16(qf1, kf1, z);
            s4[nt] = z;
        }

        const bool diag = (kt == qt);
        const int myrow = w * 16 + quad * 4;
#pragma unroll
        for (int nt = 0; nt < 4; nt++) {
            const int col = nt * 16 + l16;
#pragma unroll
            for (int r = 0; r < 4; r++) {
                float p = exp2f(s4[nt][r]);
                if (diag && col > myrow + r) p = 0.0f;
                lpart[r] += p;
                Pw[w][(quad * 4 + r) * 72 + col] = __float2bfloat16(p);
            }
        }

        asm volatile("s_waitcnt lgkmcnt(0)" ::: "memory");

        bf16x8 pf0 = *(const bf16x8*)(&Pw[w][l16 * 72 + quad * 8]);
        bf16x8 pf1 = *(const bf16x8*)(&Pw[w][l16 * 72 + 32 + quad * 8]);
#pragma unroll
        for (int dt = 0; dt < 4; dt++) {
            bf16x8 vf0 = *(const bf16x8*)((const char*)Vs[buf] + offK[0][dt]);
            bf16x8 vf1 = *(const bf16x8*)((const char*)Vs[buf] + offK[1][dt]);
            oacc[dt] = MFMA16(pf0, vf0, oacc[dt]);
            oacc[dt] = MFMA16(pf1, vf1, oacc[dt]);
        }
    }

#pragma unroll
    for (int off = 1; off < 16; off <<= 1)
#pragma unroll
        for (int r = 0; r < 4; r++)
            lpart[r] += __shfl_xor(lpart[r], off, 64);

    float rl[4];
#pragma unroll
    for (int r = 0; r < 4; r++) rl[r] = 1.0f / lpart[r];
#pragma unroll
    for (int dt = 0; dt < 4; dt++)
#pragma unroll
        for (int r = 0; r < 4; r++) {
            const int row = q0 + w * 16 + quad * 4 + r;
            outp[(size_t)(b * T + row) * 1024 + h * 64 + dt * 16 + l16] =
                __float2bfloat16(oacc[dt][r] * rl[r]);
        }
}

// --------------------------------- launcher --------------------------------
extern "C" void kernel_launch(void* const* d_in, const int* in_sizes, int n_in,
                              void* d_out, int out_size, void* d_ws, size_t ws_size,
                              hipStream_t stream) {
    const float* x     = (const float*)d_in[0];
    const float* Wqkv  = (const float*)d_in[1];
    const float* Wo    = (const float*)d_in[2];
    const float* b_o   = (const float*)d_in[3];
    const float* g1    = (const float*)d_in[4];
    const float* beta1 = (const float*)d_in[5];
    const float* g2    = (const float*)d_in[6];
    const float* beta2 = (const float*)d_in[7];
    const float* Wff1  = (const float*)d_in[8];
    const float* bff1  = (const float*)d_in[9];
    const float* Wff2  = (const float*)d_in[10];
    const float* bff2  = (const float*)d_in[11];

    char* ws = (char*)d_ws;
    size_t off = 0;
    auto alloc = [&](size_t bytes) {
        void* p = ws + off;
        off += (bytes + 255) & ~(size_t)255;
        return p;
    };
    __hip_bfloat16* Wqkv_t = (__hip_bfloat16*)alloc(3072ULL * 1024 * 2);
    __hip_bfloat16* Wo_t   = (__hip_bfloat16*)alloc(1024ULL * 1024 * 2);
    __hip_bfloat16* Wff1_t = (__hip_bfloat16*)alloc(4096ULL * 1024 * 2);
    __hip_bfloat16* Wff2_t = (__hip_bfloat16*)alloc(1024ULL * 4096 * 2);
    __hip_bfloat16* h_bf   = (__hip_bfloat16*)alloc(4096ULL * 1024 * 2);
    __hip_bfloat16* qkv_bf = (__hip_bfloat16*)alloc(4096ULL * 3072 * 2);
    __hip_bfloat16* att_bf = (__hip_bfloat16*)alloc(4096ULL * 1024 * 2);
    float*          x2     = (float*)alloc(4096ULL * 1024 * 4);
    __hip_bfloat16* ff1_bf = qkv_bf;              // dead by FF time
    __hip_bfloat16* vt     = (__hip_bfloat16*)x2; // dead before Wo-gemm writes x2

    tconv_all<<<12288, dim3(32, 8), 0, stream>>>(Wqkv, Wqkv_t, Wo, Wo_t,
                                                 Wff1, Wff1_t, Wff2, Wff2_t);

    ln_k<<<4096, 256, 0, stream>>>(x, g1, beta1, h_bf);
    gemm_k<0, 0, 0, 1><<<dim3(3072 / 128, 4096 / 128), 256, 0, stream>>>(
        h_bf, Wqkv_t, nullptr, nullptr, qkv_bf, 4096, 3072, 1024);
    vtrans_k<<<dim3(32, 32), dim3(64, 4), 0, stream>>>(qkv_bf, vt);
    attn_k<<<dim3(32, 32), 256, 0, stream>>>(qkv_bf, vt, att_bf);
    gemm12864_k<1, 0, 1, 0><<<dim3(1024 / 64, 4096 / 128), 256, 0, stream>>>(
        att_bf, Wo_t, b_o, x, x2, 4096, 1024, 1024);
    ln_k<<<4096, 256, 0, stream>>>(x2, g2, beta2, h_bf);
    gemm_k<1, 1, 0, 1><<<dim3(4096 / 128, 4096 / 128), 256, 0, stream>>>(
        h_bf, Wff1_t, bff1, nullptr, ff1_bf, 4096, 4096, 1024);
    gemm12864_k<1, 0, 1, 0><<<dim3(1024 / 64, 4096 / 128), 256, 0, stream>>>(
        ff1_bf, Wff2_t, bff2, x2, (float*)d_out, 4096, 1024, 4096);
}